// Round 7
// baseline (1818.171 us; speedup 1.0000x reference)
//
#include <hip/hip_runtime.h>

typedef __bf16 bf16x8 __attribute__((ext_vector_type(8)));
typedef float f32x4 __attribute__((ext_vector_type(4)));
typedef unsigned short u16;
typedef unsigned int u32;
typedef unsigned long long u64;

#define NF_ 133
#define EF_ 14
#define HD 300
#define KH 320   // padded K for h GEMMs (10 ksteps of 32)
#define K0 160   // padded K for h0 GEMM (133+14 -> 160)
#define K2 448   // padded K for node GEMM (133 vv | 3 gap | 300 m_v | pad)
#define NT 19    // n tiles of 16 covering 300 (pad 304)
#define SHP 2432 // shT row pitch in u16 (304 cols * 8)

__device__ __forceinline__ u16 f2bf(float f) {
    union { float f; u32 u; } v; v.f = f;
    u32 r = v.u + 0x7fffu + ((v.u >> 16) & 1u);
    return (u16)(r >> 16);
}
__device__ __forceinline__ float bf2f(u16 h) {
    union { u32 u; float f; } v; v.u = ((u32)h) << 16;
    return v.f;
}

// ---------- prep: W[K][N] fp32 -> Wt[NP][KP] bf16 (N-major, zero padded) ----------
__global__ void prep_w(const float* __restrict__ W, u16* __restrict__ Wt,
                       int K, int N, int KP, int NP, int gap) {
    int idx = blockIdx.x * 256 + threadIdx.x;
    if (idx >= NP * KP) return;
    int n = idx / KP, k = idx - n * KP;
    int kk = k;
    if (gap) kk = (k < 133) ? k : ((k >= 136 && k < 436) ? k - 3 : -1);
    float val = (kk >= 0 && kk < K && n < N) ? W[kk * N + n] : 0.f;
    Wt[idx] = f2bf(val);
}

// ---------- prep: globals -> Ar1 cols [300,512) ----------
__global__ void prep_glob(const float* __restrict__ glob, u16* __restrict__ Ar1) {
    int idx = blockIdx.x * 256 + threadIdx.x;
    if (idx >= 4096 * 212) return;
    int g = idx / 212, c = 300 + (idx - g * 212);
    float val = (c < 500) ? glob[g * 200 + (c - 300)] : 0.f;
    Ar1[g * 512 + c] = f2bf(val);
}

// ---------- mega kernel: one block (512 thr = 8 waves) per graph ----------
// Latency-bound fix (R7): every GEMM phase is batch-load -> batch-MFMA so
// 20-35 memory requests are in flight per wave instead of ~4. No reg cap
// (512,1): 8-wave block forces <=256 regs/wave anyway; R2 proved no spills
// in this tier. Each wave owns 3 n-tiles: j = t*8 + wave, t in [0,3).
// A-operand LDS layout (rows R, cols K): elem(r,c) = (c/8)*(R*8) + r*8 + (c%8)
// B-operand (hT)   layout: elem(c,k) = (k/8)*SHP + c*8 + (k%8)
__global__ __launch_bounds__(512, 1) void gnn_mega(
    const float* __restrict__ vf, const float* __restrict__ ef,
    const int* __restrict__ src, const int* __restrict__ dst,
    const u16* __restrict__ WiT, const u16* __restrict__ WmT, const u16* __restrict__ WaT,
    const float* __restrict__ bi, const float* __restrict__ bm, const float* __restrict__ ba,
    u16* __restrict__ Ar1)
{
    __shared__ u16 sm[64 * KH];     // 40960 B : A0 / m (R=64) ; later A2 (R=32)
    __shared__ u16 shT[8 * SHP];    // 38912 B : hT (B-layout)
    __shared__ u64 s_amask[32];
    __shared__ u64 s_smask[32];
    __shared__ int s_src[64];
    __shared__ unsigned char s_src8[64];

    const int g = blockIdx.x;
    const int tid = threadIdx.x;
    const int wave = tid >> 6;
    const int lane = tid & 63;
    const int lm = lane & 15;
    const int q = lane >> 4;

    if (tid < 64) {
        int sv = src[g * 64 + tid] - g * 32;
        int dv = dst[g * 64 + tid] - g * 32;
        s_src[tid] = sv;
        s_src8[tid] = (unsigned char)sv;
        #pragma unroll 1
        for (int n = 0; n < 32; ++n) {
            u64 bmA = __ballot(dv == n);
            u64 bmS = __ballot(sv == n);
            if (tid == 0) { s_amask[n] = bmA; s_smask[n] = bmS; }
        }
    }
    // zero shT pad cols 300..303
    if (tid < 128) {
        int kr = tid >> 4, c = 300 + ((tid >> 2) & 3), w = tid & 3;
        ((u32*)shT)[kr * 1216 + c * 4 + w] = 0u;
    }
    // zero sm chunks 38,39 (cols 304..319) — read by GEMM2 ks=9
    if (tid < 512) ((u32*)sm)[9728 + tid] = 0u;
    __syncthreads();

    // build A0 = [vv[src[e]] | ee | 0] (64 x 160)
    for (int idx = tid; idx < 64 * K0; idx += 512) {
        int ed = idx / K0, c = idx - ed * K0;
        float val = 0.f;
        if (c < NF_) val = vf[(size_t)(g * 32 + s_src[ed]) * (NF_ + 1) + c];
        else if (c < NF_ + EF_) val = ef[(size_t)(g * 64 + ed) * (EF_ + 1) + (c - NF_)];
        sm[((c >> 3) << 9) + (ed << 3) + (c & 7)] = f2bf(val);
    }
    __syncthreads();

    const int j0 = wave, j1 = 8 + wave, j2 = 16 + wave;   // this wave's n-tiles
    const bool ok2 = (j2 < NT);
    const int n0 = j0 * 16 + lm, n1 = j1 * 16 + lm, n2 = j2 * 16 + lm;

    // ---------- h0 GEMM (fully batched): (64x160) @ WiT ----------
    u64 h0p[3][4];
    {
        bf16x8 af[5][4];
        #pragma unroll
        for (int ks = 0; ks < 5; ++ks)
            #pragma unroll
            for (int mt = 0; mt < 4; ++mt)
                af[ks][mt] = *(const bf16x8*)&sm[((ks * 4 + q) << 9) + ((mt * 16 + lm) << 3)];
        bf16x8 wf[5][3];
        #pragma unroll
        for (int ks = 0; ks < 5; ++ks) {
            wf[ks][0] = *(const bf16x8*)&WiT[n0 * K0 + ks * 32 + q * 8];
            wf[ks][1] = *(const bf16x8*)&WiT[n1 * K0 + ks * 32 + q * 8];
            if (ok2) wf[ks][2] = *(const bf16x8*)&WiT[n2 * K0 + ks * 32 + q * 8];
        }
        f32x4 acc[3][4];
        #pragma unroll
        for (int t = 0; t < 3; ++t)
            #pragma unroll
            for (int mt = 0; mt < 4; ++mt) acc[t][mt] = (f32x4){0.f, 0.f, 0.f, 0.f};
        #pragma unroll
        for (int ks = 0; ks < 5; ++ks)
            #pragma unroll
            for (int t = 0; t < 3; ++t) {
                if (t == 2 && !ok2) continue;
                #pragma unroll
                for (int mt = 0; mt < 4; ++mt)
                    acc[t][mt] = __builtin_amdgcn_mfma_f32_16x16x32_bf16(af[ks][mt], wf[ks][t], acc[t][mt], 0, 0, 0);
            }
        #pragma unroll
        for (int t = 0; t < 3; ++t) {
            int j = t * 8 + wave;
            int n = j * 16 + lm;
            bool ok = (j < NT) && (n < HD);
            float bv = ok ? bi[n] : 0.f;
            float bmval = ok ? bm[n] : 0.f;
            #pragma unroll
            for (int mt = 0; mt < 4; ++mt) {
                u64 w = 0, wr = 0;
                #pragma unroll
                for (int r = 0; r < 4; ++r) {
                    float hv = acc[t][mt][r] + bv;
                    hv = hv > 0.f ? hv : 0.f;
                    w  |= ((u64)f2bf(hv)) << (16 * r);
                    wr |= ((u64)f2bf(hv + bmval)) << (16 * r);
                }
                h0p[t][mt] = wr;
                if (ok) *(u64*)&shT[(mt * 2 + (q >> 1)) * SHP + n * 8 + (q & 1) * 4] = w;
            }
        }
    }

    // ---------------- 3 message-passing layers ----------------
    for (int layer = 0; layer < 3; ++layer) {
        __syncthreads();
        // prefetch GEMM2 first-half weights (independent of LDS state)
        bf16x8 wA[5][3];
        #pragma unroll
        for (int ks = 0; ks < 5; ++ks) {
            wA[ks][0] = *(const bf16x8*)&WmT[n0 * KH + ks * 32 + q * 8];
            wA[ks][1] = *(const bf16x8*)&WmT[n1 * KH + ks * 32 + q * 8];
            if (ok2) wA[ks][2] = *(const bf16x8*)&WmT[n2 * KH + ks * 32 + q * 8];
        }
        // ---- GEMM1': mT[c][e] = sum_k h[k][c]*A_e[e][k], batched ----
        {
            bf16x8 af1[2][3];
            #pragma unroll
            for (int ks = 0; ks < 2; ++ks) {
                af1[ks][0] = *(const bf16x8*)&shT[(ks * 4 + q) * SHP + (j0 * 16 + lm) * 8];
                af1[ks][1] = *(const bf16x8*)&shT[(ks * 4 + q) * SHP + (j1 * 16 + lm) * 8];
                if (ok2) af1[ks][2] = *(const bf16x8*)&shT[(ks * 4 + q) * SHP + (j2 * 16 + lm) * 8];
            }
            bf16x8 bfrag[2][4];
            #pragma unroll
            for (int ks = 0; ks < 2; ++ks) {
                int kb = ks * 32 + q * 8;
                #pragma unroll
                for (int mt = 0; mt < 4; ++mt) {
                    int e = mt * 16 + lm;
                    u64 am = s_amask[s_src8[e]] & ~(1ull << (e ^ 1));
                    union { u32 w[4]; bf16x8 v; } fb;
                    #pragma unroll
                    for (int jj = 0; jj < 4; ++jj) {
                        u32 lo = (u32)((am >> (kb + 2 * jj)) & 1ull) * 0x3F80u;
                        u32 hi = (u32)((am >> (kb + 2 * jj + 1)) & 1ull) * 0x3F80u;
                        fb.w[jj] = lo | (hi << 16);
                    }
                    bfrag[ks][mt] = fb.v;
                }
            }
            #pragma unroll
            for (int t = 0; t < 3; ++t) {
                if (t == 2 && !ok2) continue;
                int j = t * 8 + wave;
                f32x4 mac[4];
                #pragma unroll
                for (int mt = 0; mt < 4; ++mt) mac[mt] = (f32x4){0.f, 0.f, 0.f, 0.f};
                #pragma unroll
                for (int ks = 0; ks < 2; ++ks)
                    #pragma unroll
                    for (int mt = 0; mt < 4; ++mt)
                        mac[mt] = __builtin_amdgcn_mfma_f32_16x16x32_bf16(af1[ks][t], bfrag[ks][mt], mac[mt], 0, 0, 0);
                #pragma unroll
                for (int mt = 0; mt < 4; ++mt) {
                    u64 w = 0;
                    #pragma unroll
                    for (int r = 0; r < 4; ++r) w |= ((u64)f2bf(mac[mt][r])) << (16 * r);
                    *(u64*)&sm[(j * 2 + (q >> 1)) * 512 + (mt * 16 + lm) * 8 + (q & 1) * 4] = w;
                }
            }
        }
        __syncthreads();
        // ---- GEMM2: h = relu(h0p + m @ Wm), two batched K-halves ----
        {
            f32x4 acc[3][4];
            #pragma unroll
            for (int t = 0; t < 3; ++t)
                #pragma unroll
                for (int mt = 0; mt < 4; ++mt) acc[t][mt] = (f32x4){0.f, 0.f, 0.f, 0.f};
            // half 1: ks 0..4 (weights already prefetched in wA)
            {
                bf16x8 afA[5][4];
                #pragma unroll
                for (int ks = 0; ks < 5; ++ks)
                    #pragma unroll
                    for (int mt = 0; mt < 4; ++mt)
                        afA[ks][mt] = *(const bf16x8*)&sm[((ks * 4 + q) << 9) + ((mt * 16 + lm) << 3)];
                #pragma unroll
                for (int ks = 0; ks < 5; ++ks)
                    #pragma unroll
                    for (int t = 0; t < 3; ++t) {
                        if (t == 2 && !ok2) continue;
                        #pragma unroll
                        for (int mt = 0; mt < 4; ++mt)
                            acc[t][mt] = __builtin_amdgcn_mfma_f32_16x16x32_bf16(afA[ks][mt], wA[ks][t], acc[t][mt], 0, 0, 0);
                    }
            }
            // half 2: ks 5..9
            {
                bf16x8 wB[5][3];
                #pragma unroll
                for (int ks = 0; ks < 5; ++ks) {
                    wB[ks][0] = *(const bf16x8*)&WmT[n0 * KH + (ks + 5) * 32 + q * 8];
                    wB[ks][1] = *(const bf16x8*)&WmT[n1 * KH + (ks + 5) * 32 + q * 8];
                    if (ok2) wB[ks][2] = *(const bf16x8*)&WmT[n2 * KH + (ks + 5) * 32 + q * 8];
                }
                bf16x8 afB[5][4];
                #pragma unroll
                for (int ks = 0; ks < 5; ++ks)
                    #pragma unroll
                    for (int mt = 0; mt < 4; ++mt)
                        afB[ks][mt] = *(const bf16x8*)&sm[(((ks + 5) * 4 + q) << 9) + ((mt * 16 + lm) << 3)];
                #pragma unroll
                for (int ks = 0; ks < 5; ++ks)
                    #pragma unroll
                    for (int t = 0; t < 3; ++t) {
                        if (t == 2 && !ok2) continue;
                        #pragma unroll
                        for (int mt = 0; mt < 4; ++mt)
                            acc[t][mt] = __builtin_amdgcn_mfma_f32_16x16x32_bf16(afB[ks][mt], wB[ks][t], acc[t][mt], 0, 0, 0);
                    }
            }
            #pragma unroll
            for (int t = 0; t < 3; ++t) {
                int j = t * 8 + wave;
                int n = j * 16 + lm;
                bool ok = (j < NT) && (n < HD);
                #pragma unroll
                for (int mt = 0; mt < 4; ++mt) {
                    u64 w = 0;
                    #pragma unroll
                    for (int r = 0; r < 4; ++r) {
                        float hv = bf2f((u16)(h0p[t][mt] >> (16 * r))) + acc[t][mt][r];
                        hv = hv > 0.f ? hv : 0.f;
                        w |= ((u64)f2bf(hv)) << (16 * r);
                    }
                    if (ok) *(u64*)&shT[(mt * 2 + (q >> 1)) * SHP + n * 8 + (q & 1) * 4] = w;
                }
            }
        }
    }
    __syncthreads();

    // ---- merged phase: A2 vv build (cols <136, 440..447) + m_vT -> sm 136..439 ----
    for (int idx = tid; idx < 32 * 136; idx += 512) {
        int n = idx / 136, c = idx - n * 136;
        float val = (c < NF_) ? vf[(size_t)(g * 32 + n) * (NF_ + 1) + c] : 0.f;
        sm[((c >> 3) << 8) + (n << 3) + (c & 7)] = f2bf(val);
    }
    if (tid < 256) {
        int n = tid >> 3, c = 440 + (tid & 7);
        sm[((c >> 3) << 8) + (n << 3) + (c & 7)] = (u16)0;
    }
    {
        bf16x8 af1[2][3];
        #pragma unroll
        for (int ks = 0; ks < 2; ++ks) {
            af1[ks][0] = *(const bf16x8*)&shT[(ks * 4 + q) * SHP + (j0 * 16 + lm) * 8];
            af1[ks][1] = *(const bf16x8*)&shT[(ks * 4 + q) * SHP + (j1 * 16 + lm) * 8];
            if (ok2) af1[ks][2] = *(const bf16x8*)&shT[(ks * 4 + q) * SHP + (j2 * 16 + lm) * 8];
        }
        bf16x8 sfrag[2][2];
        #pragma unroll
        for (int ks = 0; ks < 2; ++ks) {
            int kb = ks * 32 + q * 8;
            #pragma unroll
            for (int mt = 0; mt < 2; ++mt) {
                u64 msk = s_smask[mt * 16 + lm];
                union { u32 w[4]; bf16x8 v; } fb;
                #pragma unroll
                for (int jj = 0; jj < 4; ++jj) {
                    u32 lo = (u32)((msk >> (kb + 2 * jj)) & 1ull) * 0x3F80u;
                    u32 hi = (u32)((msk >> (kb + 2 * jj + 1)) & 1ull) * 0x3F80u;
                    fb.w[jj] = lo | (hi << 16);
                }
                sfrag[ks][mt] = fb.v;
            }
        }
        #pragma unroll
        for (int t = 0; t < 3; ++t) {
            if (t == 2 && !ok2) continue;
            int j = t * 8 + wave;
            f32x4 vacc[2];
            #pragma unroll
            for (int mt = 0; mt < 2; ++mt) vacc[mt] = (f32x4){0.f, 0.f, 0.f, 0.f};
            #pragma unroll
            for (int ks = 0; ks < 2; ++ks)
                #pragma unroll
                for (int mt = 0; mt < 2; ++mt)
                    vacc[mt] = __builtin_amdgcn_mfma_f32_16x16x32_bf16(af1[ks][t], sfrag[ks][mt], vacc[mt], 0, 0, 0);
            #pragma unroll
            for (int mt = 0; mt < 2; ++mt) {
                u64 w = 0;
                #pragma unroll
                for (int r = 0; r < 4; ++r) w |= ((u64)f2bf(vacc[mt][r])) << (16 * r);
                *(u64*)&sm[(17 + j * 2 + (q >> 1)) * 256 + (mt * 16 + lm) * 8 + (q & 1) * 4] = w;
            }
        }
    }
    __syncthreads();

    // ---- h_v = relu(A2 @ Wa + ba); mean over 32 nodes -> Ar1, two K-halves ----
    {
        f32x4 acc2[3][2];
        #pragma unroll
        for (int t = 0; t < 3; ++t)
            #pragma unroll
            for (int mt = 0; mt < 2; ++mt) acc2[t][mt] = (f32x4){0.f, 0.f, 0.f, 0.f};
        #pragma unroll
        for (int half = 0; half < 2; ++half) {
            const int kbase = half * 7;
            bf16x8 af[7][2];
            #pragma unroll
            for (int ks = 0; ks < 7; ++ks)
                #pragma unroll
                for (int mt = 0; mt < 2; ++mt)
                    af[ks][mt] = *(const bf16x8*)&sm[(((kbase + ks) * 4 + q) << 8) + ((mt * 16 + lm) << 3)];
            bf16x8 wf[7][3];
            #pragma unroll
            for (int ks = 0; ks < 7; ++ks) {
                wf[ks][0] = *(const bf16x8*)&WaT[n0 * K2 + (kbase + ks) * 32 + q * 8];
                wf[ks][1] = *(const bf16x8*)&WaT[n1 * K2 + (kbase + ks) * 32 + q * 8];
                if (ok2) wf[ks][2] = *(const bf16x8*)&WaT[n2 * K2 + (kbase + ks) * 32 + q * 8];
            }
            #pragma unroll
            for (int ks = 0; ks < 7; ++ks)
                #pragma unroll
                for (int t = 0; t < 3; ++t) {
                    if (t == 2 && !ok2) continue;
                    #pragma unroll
                    for (int mt = 0; mt < 2; ++mt)
                        acc2[t][mt] = __builtin_amdgcn_mfma_f32_16x16x32_bf16(af[ks][mt], wf[ks][t], acc2[t][mt], 0, 0, 0);
                }
        }
        #pragma unroll
        for (int t = 0; t < 3; ++t) {
            int j = t * 8 + wave;
            int n = j * 16 + lm;
            bool ok = (j < NT) && (n < HD);
            float bav = ok ? ba[n] : 0.f;
            float s = 0.f;
            #pragma unroll
            for (int mt = 0; mt < 2; ++mt)
                #pragma unroll
                for (int r = 0; r < 4; ++r) {
                    float hv = acc2[t][mt][r] + bav;
                    s += (hv > 0.f ? hv : 0.f);
                }
            s += __shfl_xor(s, 16);
            s += __shfl_xor(s, 32);
            if (ok && q == 0) Ar1[g * 512 + n] = f2bf(s * 0.03125f);
        }
    }
}

// ---------- generic LDS-free readout GEMM: C = [relu](A @ Bt^T + bias) ----------
template<int RELU, int OUTBF16>
__global__ __launch_bounds__(256, 4) void gemm_ro(
    const u16* __restrict__ A, const u16* __restrict__ Bt, const float* __restrict__ bias,
    const int KP, const int Nreal, const int outPitch, void* __restrict__ outp, const int nsteps)
{
    const int tid = threadIdx.x;
    const int wv = tid >> 6, lane = tid & 63, lm = lane & 15, q = lane >> 4;
    const int row0 = blockIdx.x * 64;
    const int col = blockIdx.y * 64 + wv * 16 + lm;
    f32x4 acc[4];
    #pragma unroll
    for (int mt = 0; mt < 4; ++mt) acc[mt] = (f32x4){0.f, 0.f, 0.f, 0.f};
    const u16* bp = Bt + col * KP + q * 8;
    const u16* ap = A + (row0 + lm) * KP + q * 8;
    for (int ks = 0; ks < nsteps; ++ks) {
        bf16x8 bfr = *(const bf16x8*)(bp + ks * 32);
        #pragma unroll
        for (int mt = 0; mt < 4; ++mt) {
            bf16x8 afr = *(const bf16x8*)(ap + mt * 16 * KP + ks * 32);
            acc[mt] = __builtin_amdgcn_mfma_f32_16x16x32_bf16(afr, bfr, acc[mt], 0, 0, 0);
        }
    }
    const float bv = (col < Nreal) ? bias[col] : 0.f;
    #pragma unroll
    for (int mt = 0; mt < 4; ++mt) {
        #pragma unroll
        for (int r = 0; r < 4; ++r) {
            int row = row0 + mt * 16 + q * 4 + r;
            float val = acc[mt][r] + bv;
            if (RELU) val = val > 0.f ? val : 0.f;
            if (OUTBF16) {
                ((u16*)outp)[row * outPitch + col] = (col < Nreal) ? f2bf(val) : (u16)0;
            } else {
                if (col < Nreal) ((float*)outp)[row * outPitch + col] = val;
            }
        }
    }
}

extern "C" void kernel_launch(void* const* d_in, const int* in_sizes, int n_in,
                              void* d_out, int out_size, void* d_ws, size_t ws_size,
                              hipStream_t stream) {
    (void)in_sizes; (void)n_in; (void)out_size; (void)ws_size;
    const float* v   = (const float*)d_in[0];
    const float* e   = (const float*)d_in[1];
    const float* glb = (const float*)d_in[2];
    const float* Wi  = (const float*)d_in[3];
    const float* bi  = (const float*)d_in[4];
    const float* Wm  = (const float*)d_in[5];
    const float* bm  = (const float*)d_in[6];
    const float* Wa  = (const float*)d_in[7];
    const float* ba  = (const float*)d_in[8];
    const float* Wr1 = (const float*)d_in[9];
    const float* br1 = (const float*)d_in[10];
    const float* Wr2 = (const float*)d_in[11];
    const float* br2 = (const float*)d_in[12];
    const float* Wr3 = (const float*)d_in[13];
    const float* br3 = (const float*)d_in[14];
    const int* src = (const int*)d_in[15];
    const int* dst = (const int*)d_in[16];

    char* ws = (char*)d_ws;
    u16* WiT  = (u16*)(ws + 0);            // 304*160*2  =   97280
    u16* WmT  = (u16*)(ws + 97280);        // 304*320*2  =  194560
    u16* WaT  = (u16*)(ws + 291840);       // 304*448*2  =  272384
    u16* Wr1T = (u16*)(ws + 564224);       // 576*512*2  =  589824
    u16* Wr2T = (u16*)(ws + 1154048);      // 384*576*2  =  442368
    u16* Wr3T = (u16*)(ws + 1596416);      //  64*384*2  =   49152
    u16* Ar1  = (u16*)(ws + 1645568);      // 4096*512*2 = 4194304
    u16* Ar2  = (u16*)(ws + 5839872);      // 4096*576*2 = 4718592
    u16* Ar3  = (u16*)(ws + 10558464);     // 4096*384*2 = 3145728

    prep_w<<<190,  256, 0, stream>>>(Wi,  WiT,  147, 300, 160, 304, 0);
    prep_w<<<380,  256, 0, stream>>>(Wm,  WmT,  300, 300, 320, 304, 0);
    prep_w<<<532,  256, 0, stream>>>(Wa,  WaT,  433, 300, 448, 304, 1);
    prep_w<<<1152, 256, 0, stream>>>(Wr1, Wr1T, 500, 550, 512, 576, 0);
    prep_w<<<864,  256, 0, stream>>>(Wr2, Wr2T, 550, 378, 576, 384, 0);
    prep_w<<<96,   256, 0, stream>>>(Wr3, Wr3T, 378, 12,  384, 64,  0);
    prep_glob<<<3392, 256, 0, stream>>>(glb, Ar1);

    gnn_mega<<<4096, 512, 0, stream>>>(v, e, src, dst, WiT, WmT, WaT, bi, bm, ba, Ar1);

    gemm_ro<1, 1><<<dim3(64, 9), 256, 0, stream>>>(Ar1, Wr1T, br1, 512, 550, 576, Ar2, 16);
    gemm_ro<1, 1><<<dim3(64, 6), 256, 0, stream>>>(Ar2, Wr2T, br2, 576, 378, 384, Ar3, 18);
    gemm_ro<0, 0><<<dim3(64, 1), 256, 0, stream>>>(Ar3, Wr3T, br3, 384, 12, 12, d_out, 12);
}